// Round 2
// baseline (251.587 us; speedup 1.0000x reference)
//
#include <hip/hip_runtime.h>

// PointNet 3-NN feature interpolation.
// Phase 1: per-query 3-NN + inverse-distance weights -> workspace (SoA).
// Phase 2: per-(b,d) row staged in LDS, gather+weighted-sum, coalesced out.

constexpr int QPW = 4;   // queries per wave in phase 1

__device__ __forceinline__ void insert3(float dv[3], int iv[3], float d, int i) {
    if (d < dv[2]) {
        if (d < dv[1]) {
            dv[2] = dv[1]; iv[2] = iv[1];
            if (d < dv[0]) { dv[1] = dv[0]; iv[1] = iv[0]; dv[0] = d; iv[0] = i; }
            else           { dv[1] = d;     iv[1] = i; }
        } else { dv[2] = d; iv[2] = i; }
    }
}

__global__ __launch_bounds__(256)
void knn3_kernel(const float* __restrict__ xyz1, const float* __restrict__ xyz2,
                 int B, int N, int S,
                 int* __restrict__ idx0, int* __restrict__ idx1, int* __restrict__ idx2,
                 float* __restrict__ w0, float* __restrict__ w1, float* __restrict__ w2)
{
#pragma clang fp contract(off)
    const int lane = threadIdx.x & 63;
    const int gwave = blockIdx.x * (blockDim.x >> 6) + (threadIdx.x >> 6);
    const int qBase = gwave * QPW;
    const int BS = B * S;
    if (qBase >= BS) return;
    const int b = qBase / S;          // S % QPW == 0 -> whole wave in one batch

    const float* __restrict__ x1p = xyz1 + (size_t)b * 3 * N;
    const float* __restrict__ y1p = x1p + N;
    const float* __restrict__ z1p = y1p + N;
    const float* __restrict__ q2p = xyz2 + (size_t)b * 3 * S;

    float qx[QPW], qy[QPW], qz[QPW], qss[QPW];
    float dv[QPW][3];
    int   iv[QPW][3];
#pragma unroll
    for (int j = 0; j < QPW; ++j) {
        int s = qBase + j - b * S;
        float x = q2p[s];
        float y = q2p[S + s];
        float z = q2p[2 * S + s];
        qx[j] = x; qy[j] = y; qz[j] = z;
        qss[j] = (x * x + y * y) + z * z;   // match np sum order
        dv[j][0] = dv[j][1] = dv[j][2] = 3.4e38f;
        iv[j][0] = iv[j][1] = iv[j][2] = 0;
    }

    for (int n = lane; n < N; n += 64) {
        float x1 = x1p[n], y1 = y1p[n], z1 = z1p[n];
        float s1 = (x1 * x1 + y1 * y1) + z1 * z1;
#pragma unroll
        for (int j = 0; j < QPW; ++j) {
            float dot = (qx[j] * x1 + qy[j] * y1) + qz[j] * z1;
            float t = qss[j] + s1;
            float d = t - 2.0f * dot;       // identical rounding to reference
            insert3(dv[j], iv[j], d, n);
        }
    }

    // butterfly merge across 64 lanes
    for (int off = 32; off >= 1; off >>= 1) {
#pragma unroll
        for (int j = 0; j < QPW; ++j) {
            float pd0 = __shfl_xor(dv[j][0], off);
            float pd1 = __shfl_xor(dv[j][1], off);
            float pd2 = __shfl_xor(dv[j][2], off);
            int   pi0 = __shfl_xor(iv[j][0], off);
            int   pi1 = __shfl_xor(iv[j][1], off);
            int   pi2 = __shfl_xor(iv[j][2], off);
            insert3(dv[j], iv[j], pd0, pi0);
            insert3(dv[j], iv[j], pd1, pi1);
            insert3(dv[j], iv[j], pd2, pi2);
        }
    }

    if (lane == 0) {
#pragma unroll
        for (int j = 0; j < QPW; ++j) {
            int q = qBase + j;
            float r0 = 1.0f / (dv[j][0] + 1e-8f);
            float r1 = 1.0f / (dv[j][1] + 1e-8f);
            float r2 = 1.0f / (dv[j][2] + 1e-8f);
            float sum = (r0 + r1) + r2;     // match np sum order
            idx0[q] = iv[j][0]; idx1[q] = iv[j][1]; idx2[q] = iv[j][2];
            w0[q] = r0 / sum;  w1[q] = r1 / sum;  w2[q] = r2 / sum;
        }
    }
}

__global__ __launch_bounds__(256)
void interp_kernel(const float* __restrict__ points1,
                   const int* __restrict__ idx0, const int* __restrict__ idx1,
                   const int* __restrict__ idx2,
                   const float* __restrict__ w0, const float* __restrict__ w1,
                   const float* __restrict__ w2,
                   float* __restrict__ out, int N, int S, int D)
{
#pragma clang fp contract(off)
    __shared__ float row[8192];           // N == 8192 for this problem
    const int bd = blockIdx.x;            // b*D + d
    const int b  = bd / D;
    const float* __restrict__ src = points1 + (size_t)bd * N;

    for (int i = threadIdx.x * 4; i < N; i += blockDim.x * 4) {
        *reinterpret_cast<float4*>(&row[i]) =
            *reinterpret_cast<const float4*>(src + i);
    }
    __syncthreads();

    float* __restrict__ dst = out + (size_t)bd * S;
    const int qb = b * S;
    for (int s = threadIdx.x; s < S; s += blockDim.x) {
        int q = qb + s;
        float a = row[idx0[q]] * w0[q];
        float c = row[idx1[q]] * w1[q];
        float e = row[idx2[q]] * w2[q];
        dst[s] = (a + c) + e;             // match np sum order
    }
}

extern "C" void kernel_launch(void* const* d_in, const int* in_sizes, int n_in,
                              void* d_out, int out_size, void* d_ws, size_t ws_size,
                              hipStream_t stream) {
    const float* xyz1    = (const float*)d_in[0];
    const float* xyz2    = (const float*)d_in[1];
    const float* points1 = (const float*)d_in[2];
    float* out = (float*)d_out;

    const int B = 8;
    const int N = in_sizes[0] / (3 * B);
    const int S = in_sizes[1] / (3 * B);
    const int D = in_sizes[2] / (B * N);
    const int BS = B * S;

    int*   idx0 = (int*)d_ws;
    int*   idx1 = idx0 + BS;
    int*   idx2 = idx1 + BS;
    float* w0   = (float*)(idx2 + BS);
    float* w1   = w0 + BS;
    float* w2   = w1 + BS;

    // Phase 1: one wave per QPW queries, 4 waves per block.
    int waves  = (BS + QPW - 1) / QPW;
    int blocks = (waves + 3) / 4;
    knn3_kernel<<<blocks, 256, 0, stream>>>(xyz1, xyz2, B, N, S,
                                            idx0, idx1, idx2, w0, w1, w2);

    // Phase 2: one block per (b,d) row.
    interp_kernel<<<B * D, 256, 0, stream>>>(points1, idx0, idx1, idx2,
                                             w0, w1, w2, out, N, S, D);
}

// Round 3
// 107.689 us; speedup vs baseline: 2.3362x; 2.3362x over previous
//
#include <hip/hip_runtime.h>

// PointNet 3-NN feature interpolation, v2.
// Phase 1: knn3_partial — query-per-thread, point-chunk staged in LDS with
//          precomputed norms, broadcast reads, branchless top-3. Partials -> ws.
// Phase 2: knn3_merge — merge per-chunk top-3s, compute weights.
// Phase 3: interp — per-(b,d) row staged in LDS, gather+weighted-sum.

constexpr int QT = 256;        // queries per block in phase 1
constexpr int MAXCHUNK = 1024; // LDS capacity (float4 per point)

__device__ __forceinline__ void insert3b(float& d0, float& d1, float& d2,
                                         int& i0, int& i1, int& i2,
                                         float d, int n) {
    bool c0 = d < d0, c1 = d < d1, c2 = d < d2;
    float nd2 = c1 ? d1 : (c2 ? d : d2);
    int   ni2 = c1 ? i1 : (c2 ? n : i2);
    float nd1 = c0 ? d0 : (c1 ? d : d1);
    int   ni1 = c0 ? i0 : (c1 ? n : i1);
    float nd0 = c0 ? d  : d0;
    int   ni0 = c0 ? n  : i0;
    d0 = nd0; d1 = nd1; d2 = nd2;
    i0 = ni0; i1 = ni1; i2 = ni2;
}

__global__ __launch_bounds__(256)
void knn3_partial(const float* __restrict__ xyz1, const float* __restrict__ xyz2,
                  int B, int N, int S, int cs /* chunk size */,
                  float* __restrict__ pd0, float* __restrict__ pd1,
                  float* __restrict__ pd2,
                  int* __restrict__ pi0, int* __restrict__ pi1,
                  int* __restrict__ pi2)
{
#pragma clang fp contract(off)
    __shared__ float4 spt[MAXCHUNK];   // {x, y, z, norm}
    const int tid = threadIdx.x;
    const int q   = blockIdx.x * QT + tid;   // global query id
    const int c   = blockIdx.y;              // chunk id
    const int BS  = B * S;
    const int b   = q / S;                   // QT divides S -> b uniform in block
    const int s   = q - b * S;
    const int n0  = c * cs;

    // ---- stage chunk: xyz + norm, coalesced float4 loads ----
    const float* __restrict__ bx = xyz1 + (size_t)b * 3 * N + n0;
    const float* __restrict__ by = bx + N;
    const float* __restrict__ bz = by + N;
    for (int i = tid * 4; i < cs; i += 256 * 4) {
        float4 vx = *reinterpret_cast<const float4*>(bx + i);
        float4 vy = *reinterpret_cast<const float4*>(by + i);
        float4 vz = *reinterpret_cast<const float4*>(bz + i);
        spt[i + 0] = make_float4(vx.x, vy.x, vz.x, (vx.x*vx.x + vy.x*vy.x) + vz.x*vz.x);
        spt[i + 1] = make_float4(vx.y, vy.y, vz.y, (vx.y*vx.y + vy.y*vy.y) + vz.y*vz.y);
        spt[i + 2] = make_float4(vx.z, vy.z, vz.z, (vx.z*vx.z + vy.z*vy.z) + vz.z*vz.z);
        spt[i + 3] = make_float4(vx.w, vy.w, vz.w, (vx.w*vx.w + vy.w*vy.w) + vz.w*vz.w);
    }
    __syncthreads();

    // ---- query data ----
    const float* __restrict__ q2p = xyz2 + (size_t)b * 3 * S;
    const float qx = q2p[s];
    const float qy = q2p[S + s];
    const float qz = q2p[2 * S + s];
    const float qss = (qx * qx + qy * qy) + qz * qz;   // match np sum order

    float d0 = 3.4e38f, d1 = 3.4e38f, d2 = 3.4e38f;
    int   i0 = 0, i1 = 0, i2 = 0;

#pragma unroll 4
    for (int k = 0; k < cs; ++k) {
        float4 p = spt[k];                       // wave-uniform addr -> broadcast
        float dot = (qx * p.x + qy * p.y) + qz * p.z;
        float t   = qss + p.w;
        float d   = t - 2.0f * dot;              // identical rounding to reference
        insert3b(d0, d1, d2, i0, i1, i2, d, n0 + k);
    }

    const size_t off = (size_t)c * BS + q;
    pd0[off] = d0; pd1[off] = d1; pd2[off] = d2;
    pi0[off] = i0; pi1[off] = i1; pi2[off] = i2;
}

__global__ __launch_bounds__(256)
void knn3_merge(const float* __restrict__ pd0, const float* __restrict__ pd1,
                const float* __restrict__ pd2,
                const int* __restrict__ pi0, const int* __restrict__ pi1,
                const int* __restrict__ pi2,
                int nChunk, int BS,
                int* __restrict__ idx0, int* __restrict__ idx1, int* __restrict__ idx2,
                float* __restrict__ w0, float* __restrict__ w1, float* __restrict__ w2)
{
#pragma clang fp contract(off)
    const int q = blockIdx.x * 256 + threadIdx.x;
    if (q >= BS) return;
    float d0 = 3.4e38f, d1 = 3.4e38f, d2 = 3.4e38f;
    int   i0 = 0, i1 = 0, i2 = 0;
    // chunks in ascending order; within a chunk partials are ascending (value,
    // index) — strict-< insertion preserves top_k's lowest-index tie-breaking.
    for (int c = 0; c < nChunk; ++c) {
        const size_t off = (size_t)c * BS + q;
        insert3b(d0, d1, d2, i0, i1, i2, pd0[off], pi0[off]);
        insert3b(d0, d1, d2, i0, i1, i2, pd1[off], pi1[off]);
        insert3b(d0, d1, d2, i0, i1, i2, pd2[off], pi2[off]);
    }
    const float r0 = 1.0f / (d0 + 1e-8f);
    const float r1 = 1.0f / (d1 + 1e-8f);
    const float r2 = 1.0f / (d2 + 1e-8f);
    const float sum = (r0 + r1) + r2;            // match np sum order
    idx0[q] = i0; idx1[q] = i1; idx2[q] = i2;
    w0[q] = r0 / sum; w1[q] = r1 / sum; w2[q] = r2 / sum;
}

__global__ __launch_bounds__(256)
void interp_kernel(const float* __restrict__ points1,
                   const int* __restrict__ idx0, const int* __restrict__ idx1,
                   const int* __restrict__ idx2,
                   const float* __restrict__ w0, const float* __restrict__ w1,
                   const float* __restrict__ w2,
                   float* __restrict__ out, int N, int S, int D)
{
#pragma clang fp contract(off)
    __shared__ float row[8192];           // N == 8192 for this problem
    const int bd = blockIdx.x;            // b*D + d
    const int b  = bd / D;
    const float* __restrict__ src = points1 + (size_t)bd * N;

    for (int i = threadIdx.x * 4; i < N; i += blockDim.x * 4) {
        *reinterpret_cast<float4*>(&row[i]) =
            *reinterpret_cast<const float4*>(src + i);
    }
    __syncthreads();

    float* __restrict__ dst = out + (size_t)bd * S;
    const int qb = b * S;
    for (int s = threadIdx.x; s < S; s += blockDim.x) {
        int q = qb + s;
        float a = row[idx0[q]] * w0[q];
        float c = row[idx1[q]] * w1[q];
        float e = row[idx2[q]] * w2[q];
        dst[s] = (a + c) + e;             // match np sum order
    }
}

extern "C" void kernel_launch(void* const* d_in, const int* in_sizes, int n_in,
                              void* d_out, int out_size, void* d_ws, size_t ws_size,
                              hipStream_t stream) {
    const float* xyz1    = (const float*)d_in[0];
    const float* xyz2    = (const float*)d_in[1];
    const float* points1 = (const float*)d_in[2];
    float* out = (float*)d_out;

    const int B = 8;
    const int N = in_sizes[0] / (3 * B);
    const int S = in_sizes[1] / (3 * B);
    const int D = in_sizes[2] / (B * N);
    const int BS = B * S;

    // choose chunk count: prefer 16 chunks (cs=512, better occupancy),
    // fall back to 8 (cs=1024) if workspace is tight.
    int nChunk = 16;
    auto wsNeed = [&](int nc) {
        return (size_t)nc * BS * 6 * 4 + (size_t)BS * 6 * 4;
    };
    if (wsNeed(16) > ws_size) nChunk = 8;
    const int cs = N / nChunk;            // N=8192 -> 512 or 1024 (<= MAXCHUNK)

    float* pd0 = (float*)d_ws;
    float* pd1 = pd0 + (size_t)nChunk * BS;
    float* pd2 = pd1 + (size_t)nChunk * BS;
    int*   pi0 = (int*)(pd2 + (size_t)nChunk * BS);
    int*   pi1 = pi0 + (size_t)nChunk * BS;
    int*   pi2 = pi1 + (size_t)nChunk * BS;
    int*   idx0 = pi2 + (size_t)nChunk * BS;
    int*   idx1 = idx0 + BS;
    int*   idx2 = idx1 + BS;
    float* w0   = (float*)(idx2 + BS);
    float* w1   = w0 + BS;
    float* w2   = w1 + BS;

    dim3 g1(BS / QT, nChunk);
    knn3_partial<<<g1, 256, 0, stream>>>(xyz1, xyz2, B, N, S, cs,
                                         pd0, pd1, pd2, pi0, pi1, pi2);

    knn3_merge<<<(BS + 255) / 256, 256, 0, stream>>>(pd0, pd1, pd2, pi0, pi1, pi2,
                                                     nChunk, BS,
                                                     idx0, idx1, idx2, w0, w1, w2);

    interp_kernel<<<B * D, 256, 0, stream>>>(points1, idx0, idx1, idx2,
                                             w0, w1, w2, out, N, S, D);
}